// Round 3
// baseline (525.633 us; speedup 1.0000x reference)
//
#include <hip/hip_runtime.h>

typedef __attribute__((ext_vector_type(8))) short short8;
typedef __attribute__((ext_vector_type(4))) float f32x4;
typedef __attribute__((ext_vector_type(4))) unsigned short ushx4;
typedef __attribute__((ext_vector_type(8))) unsigned short ushx8;

#define E_EDGES 800000
#define TILE 64
#define NTILES (E_EDGES / TILE)   // 12500 exact

// ws layout, ushort units (tables only now)
#define WS_TSRC 0
#define WS_TDST 12288
#define WS_TSTEP 24576
#define WS_TEQ 27136
#define WS_W2T 27392      // [n=0..127][k=0..127], W2T[n][k] = W[256+k][n]
#define WS_WRBFT 43776    // [n=0..127][k=0..31],  zero-padded past k=6

__device__ __forceinline__ unsigned short f2bf(float f) {
    unsigned int u = __float_as_uint(f);
    u += 0x7fffu + ((u >> 16) & 1u);   // RNE
    return (unsigned short)(u >> 16);
}
__device__ __forceinline__ float bf2f(unsigned short u) {
    return __uint_as_float(((unsigned int)u) << 16);
}
__device__ __forceinline__ float silu_f(float v) {
    return v * __builtin_amdgcn_rcpf(1.0f + __expf(-v));
}

// ---------------- Kernel P: fold small-vocab gathers through W into tables ----
__global__ void precompute_kernel(const float* __restrict__ emb,
                                  const float* __restrict__ stept,
                                  const float* __restrict__ eqt,
                                  const float* __restrict__ Wrbf,
                                  const float* __restrict__ W,
                                  const float* __restrict__ bias,
                                  unsigned short* __restrict__ ws) {
    const int b = blockIdx.x;
    const int j = threadIdx.x;   // 128 threads
    if (b < 214) {
        const float* tab; int woff; unsigned short* outp; float acc = 0.f;
        if (b < 96)       { tab = emb   + b*128;        woff = 0;   outp = ws + WS_TSRC  + b*128; }
        else if (b < 192) { tab = emb   + (b-96)*128;   woff = 128; outp = ws + WS_TDST  + (b-96)*128; }
        else if (b < 212) { tab = stept + (b-192)*128;  woff = 384; outp = ws + WS_TSTEP + (b-192)*128; }
        else              { tab = eqt   + (b-212)*128;  woff = 512; outp = ws + WS_TEQ   + (b-212)*128; acc = bias[j]; }
        #pragma unroll 4
        for (int k = 0; k < 128; ++k)
            acc += tab[k] * W[(woff + k)*128 + j];
        outp[j] = f2bf(acc);
    } else {
        const int n = b - 214;   // 0..127
        ws[WS_W2T + n*128 + j] = f2bf(W[(256 + j)*128 + n]);
        if (j < 32)
            ws[WS_WRBFT + n*32 + j] = (j < 6) ? f2bf(Wrbf[j*128 + n]) : (unsigned short)0;
    }
}

// ---------------- Kernel M: fully fused persistent edge kernel ----------------
// Wave roles per tile (producer work pipelined one tile ahead):
//   wave 0: meta (Z/step/equiv offsets) for tile+stride -> meta_l
//   wave 1: rbf -> bf16x8 A-fragments for tile+stride   -> rbf8_l
//   waves 2,3: d prefetch for tile+stride; rbf_env compute+store for current
__global__ __launch_bounds__(256, 3)
void edge_kernel(const unsigned short* __restrict__ ws,
                 const int* __restrict__ Z, const int* __restrict__ stepv,
                 const int* __restrict__ src, const int* __restrict__ dst,
                 const int* __restrict__ equiv, const float* __restrict__ rbf,
                 const float* __restrict__ dvec,
                 const float* __restrict__ brbf_g, float* __restrict__ out) {
    __shared__ alignas(16) unsigned short rbf_a[TILE*136];  // 17.0 KB
    __shared__ alignas(16) float sumbuf[TILE*132];          // 33.0 KB
    __shared__ alignas(16) int4  meta_l[TILE];              // 1 KB
    __shared__ alignas(16) ushx8 rbf8_l[TILE];              // 1 KB  (total 52.0 KB -> 3 blk/CU)

    const int t = threadIdx.x;
    const int lane = t & 63;
    const int w = t >> 6;
    const int q = lane >> 4;
    const int r = lane & 15;
    const int mh = w >> 1;        // edge sub-tile [mh*16, +16)
    const int nh = w & 1;         // col half [nh*64, +64)
    const int arow = mh*16 + r;
    const int half = w - 2;       // for env waves (2,3): 0/1

    const unsigned short* W2T = ws + WS_W2T;
    const unsigned short* WRB = ws + WS_WRBFT;
    float* const env_out = out + (long)E_EDGES*128;

    // block-invariant B-fragments in VGPRs
    short8 w2f[16];
    short8 wrbf[4];
    float  brbf[4];
    #pragma unroll
    for (int nt = 0; nt < 4; ++nt) {
        const int n = nh*64 + nt*16 + r;
        #pragma unroll
        for (int ks = 0; ks < 4; ++ks)
            w2f[nt*4+ks] = *(const short8*)(W2T + n*128 + ks*32 + q*8);
        wrbf[nt] = *(const short8*)(WRB + n*32 + q*8);
        brbf[nt] = brbf_g[n];
    }

    // phase-1a coalesced-gather coordinates: 16 lanes cover one 256 B table row
    const int el8 = t >> 4;          // edge sub-index 0..15
    const int c0  = (t & 15) * 8;    // col chunk (8 ushorts = 16 B)

    // ---- prologue: produce pipeline data for the first tile ----
    float dcur = 0.f;
    {
        const int bn = blockIdx.x * TILE;
        if (w == 0) {
            const int s  = src[bn + lane];
            const int dd = dst[bn + lane];
            const int qe = equiv[bn + lane];
            meta_l[lane] = make_int4(Z[s] << 7, Z[dd] << 7, stepv[s] << 7, qe << 7);
        } else if (w == 1) {
            const float* rp = rbf + (long)(bn + lane)*6;
            const float2 ra = *(const float2*)rp;
            const float2 rb = *(const float2*)(rp + 2);
            const float2 rc = *(const float2*)(rp + 4);
            ushx8 v;
            v[0] = f2bf(ra.x); v[1] = f2bf(ra.y);
            v[2] = f2bf(rb.x); v[3] = f2bf(rb.y);
            v[4] = f2bf(rc.x); v[5] = f2bf(rc.y);
            v[6] = 0; v[7] = 0;
            rbf8_l[lane] = v;
        } else {
            dcur = dvec[bn + lane];
        }
        __syncthreads();
    }

    for (int tile = blockIdx.x; tile < NTILES; tile += gridDim.x) {
        const int base = tile * TILE;
        const int tnext = tile + gridDim.x;
        const int tclamp = (tnext < NTILES) ? tnext : tile;
        const int bn = tclamp * TILE;

        // ---- issue first-level prefetch loads for next tile (no deps) ----
        int sN = 0, dN = 0, qN = 0;
        float2 ra, rb, rc;
        float dnew = dcur;
        if (w == 0) {
            sN = src[bn + lane]; dN = dst[bn + lane]; qN = equiv[bn + lane];
        } else if (w == 1) {
            const float* rp = rbf + (long)(bn + lane)*6;
            ra = *(const float2*)rp;
            rb = *(const float2*)(rp + 2);
            rc = *(const float2*)(rp + 4);
        } else {
            dnew = dvec[bn + lane];
        }

        // ---- phase 1a: table-sum prestage, coalesced row reads ----
        #pragma unroll
        for (int i = 0; i < 4; ++i) {
            const int e = i*16 + el8;
            const int4 mo = meta_l[e];                 // LDS broadcast across 16 lanes
            ushx8 u0 = *(const ushx8*)(ws + WS_TSRC  + mo.x + c0);
            ushx8 u1 = *(const ushx8*)(ws + WS_TDST  + mo.y + c0);
            ushx8 u2 = *(const ushx8*)(ws + WS_TSTEP + mo.z + c0);
            ushx8 u3 = *(const ushx8*)(ws + WS_TEQ   + mo.w + c0);
            float* srow = sumbuf + e*132 + c0;
            f32x4 sv0, sv1;
            #pragma unroll
            for (int k = 0; k < 4; ++k) {
                sv0[k] = bf2f(u0[k])   + bf2f(u1[k])   + bf2f(u2[k])   + bf2f(u3[k]);
                sv1[k] = bf2f(u0[k+4]) + bf2f(u1[k+4]) + bf2f(u2[k+4]) + bf2f(u3[k+4]);
            }
            *(f32x4*)(srow)     = sv0;
            *(f32x4*)(srow + 4) = sv1;
        }

        // ---- phase 1b: mini-MFMA rbf_a = silu(rbf @ W_rbf + b) ----
        {
            short8 a0 = (short8)0;
            if (q == 0) a0 = *(const short8*)(rbf8_l + arow);
            #pragma unroll
            for (int nt = 0; nt < 4; ++nt) {
                const float bb = brbf[nt];
                f32x4 c = {bb, bb, bb, bb};
                c = __builtin_amdgcn_mfma_f32_16x16x32_bf16(a0, wrbf[nt], c, 0, 0, 0);
                const int col = nh*64 + nt*16 + r;
                #pragma unroll
                for (int reg = 0; reg < 4; ++reg)
                    rbf_a[(mh*16 + q*4 + reg)*136 + col] = f2bf(silu_f(c[reg]));
            }
        }
        __syncthreads();

        // ---- second-level gathers for next tile (hidden under phase-2 compute)
        int zs = 0, zd = 0, st = 0;
        if (w == 0) { zs = Z[sN]; zd = Z[dN]; st = stepv[sN]; }

        // ---- phase 2: main MFMA (C init = table sums), silu, direct stores ----
        f32x4 acc[4];
        #pragma unroll
        for (int nt = 0; nt < 4; ++nt) {
            const int col = nh*64 + nt*16 + r;
            #pragma unroll
            for (int reg = 0; reg < 4; ++reg)
                acc[nt][reg] = sumbuf[(mh*16 + q*4 + reg)*132 + col];
        }
        #pragma unroll
        for (int ks = 0; ks < 4; ++ks) {
            short8 a = *(const short8*)(rbf_a + arow*136 + ks*32 + q*8);
            #pragma unroll
            for (int nt = 0; nt < 4; ++nt)
                acc[nt] = __builtin_amdgcn_mfma_f32_16x16x32_bf16(a, w2f[nt*4+ks], acc[nt], 0, 0, 0);
        }
        #pragma unroll
        for (int nt = 0; nt < 4; ++nt) {
            const int col = nh*64 + nt*16 + r;
            #pragma unroll
            for (int reg = 0; reg < 4; ++reg)
                __builtin_nontemporal_store(silu_f(acc[nt][reg]),
                    &out[(long)(base + mh*16 + q*4 + reg)*128 + col]);
        }

        // ---- producer writes (consumed next iteration, after end barrier) ----
        if (w == 0) {
            meta_l[lane] = make_int4(zs << 7, zd << 7, st << 7, qN << 7);
        } else if (w == 1) {
            ushx8 v;
            v[0] = f2bf(ra.x); v[1] = f2bf(ra.y);
            v[2] = f2bf(rb.x); v[3] = f2bf(rb.y);
            v[4] = f2bf(rc.x); v[5] = f2bf(rc.y);
            v[6] = 0; v[7] = 0;
            rbf8_l[lane] = v;
        } else {
            // rbf_env for CURRENT tile (dcur loaded last iteration / prologue)
            const float x = dcur * 0.2f;
            const float inv = __builtin_amdgcn_rcpf(x);
            const float x2 = x*x;
            const float x5 = x2*x2*x;
            const float env = inv + x5*(-28.f + x*(48.f - 21.f*x));
            float* ep = env_out + (long)(base + lane)*6 + half*3;
            #pragma unroll
            for (int j = 0; j < 3; ++j) {
                const int rr = half*3 + j;
                const float sv = __sinf(x * (3.14159265358979f * (rr + 1)));
                __builtin_nontemporal_store(env * sv * inv, ep + j);
            }
            dcur = dnew;
        }
        __syncthreads();   // protect sumbuf/rbf_a/meta_l/rbf8_l for next tile
    }
}

extern "C" void kernel_launch(void* const* d_in, const int* in_sizes, int n_in,
                              void* d_out, int out_size, void* d_ws, size_t ws_size,
                              hipStream_t stream) {
    const int*   Z     = (const int*)d_in[0];
    const int*   stepv = (const int*)d_in[1];
    const int*   src   = (const int*)d_in[2];
    const int*   dst   = (const int*)d_in[3];
    const int*   equiv = (const int*)d_in[4];
    const float* rbf   = (const float*)d_in[5];
    const float* dvec  = (const float*)d_in[6];
    const float* emb   = (const float*)d_in[7];
    const float* stept = (const float*)d_in[8];
    const float* eqt   = (const float*)d_in[9];
    const float* Wrbf  = (const float*)d_in[10];
    const float* brbf  = (const float*)d_in[11];
    const float* W     = (const float*)d_in[12];
    const float* bias  = (const float*)d_in[13];
    unsigned short* ws = (unsigned short*)d_ws;
    float* out = (float*)d_out;

    precompute_kernel<<<342, 128, 0, stream>>>(emb, stept, eqt, Wrbf, W, bias, ws);
    edge_kernel<<<768, 256, 0, stream>>>(ws, Z, stepv, src, dst, equiv, rbf, dvec, brbf, out);
}

// Round 4
// 497.948 us; speedup vs baseline: 1.0556x; 1.0556x over previous
//
#include <hip/hip_runtime.h>

typedef __attribute__((ext_vector_type(8))) short short8;
typedef __attribute__((ext_vector_type(4))) float f32x4;
typedef __attribute__((ext_vector_type(4))) unsigned short ushx4;
typedef __attribute__((ext_vector_type(8))) unsigned short ushx8;

#define E_EDGES 800000
#define TILE 64
#define NTILES (E_EDGES / TILE)   // 12500 exact

// ws layout, ushort units (tables)
#define WS_TSRC 0
#define WS_TDST 12288
#define WS_TSTEP 24576
#define WS_TEQ 27136
#define WS_W2T 27392      // [n=0..127][k=0..127], W2T[n][k] = W[256+k][n]
#define WS_WRBFT 43776    // [n=0..127][k=0..31],  zero-padded past k=6
// byte offsets for per-edge prestage (tables end at 95744 B)
#define WSB_META 131072u                    // int4[E] = 12.8 MB
#define WSB_RBF8 (WSB_META + 16u*E_EDGES)   // ushx8[E] = 12.8 MB

__device__ __forceinline__ unsigned short f2bf(float f) {
    unsigned int u = __float_as_uint(f);
    u += 0x7fffu + ((u >> 16) & 1u);   // RNE
    return (unsigned short)(u >> 16);
}
__device__ __forceinline__ float bf2f(unsigned short u) {
    return __uint_as_float(((unsigned int)u) << 16);
}
__device__ __forceinline__ float silu_f(float v) {
    return v * __builtin_amdgcn_rcpf(1.0f + __expf(-v));
}

// ---------------- Kernel P: fold small-vocab gathers through W into tables ----
__global__ void precompute_kernel(const float* __restrict__ emb,
                                  const float* __restrict__ stept,
                                  const float* __restrict__ eqt,
                                  const float* __restrict__ Wrbf,
                                  const float* __restrict__ W,
                                  const float* __restrict__ bias,
                                  unsigned short* __restrict__ ws) {
    const int b = blockIdx.x;
    const int j = threadIdx.x;   // 128 threads
    if (b < 214) {
        const float* tab; int woff; unsigned short* outp; float acc = 0.f;
        if (b < 96)       { tab = emb   + b*128;        woff = 0;   outp = ws + WS_TSRC  + b*128; }
        else if (b < 192) { tab = emb   + (b-96)*128;   woff = 128; outp = ws + WS_TDST  + (b-96)*128; }
        else if (b < 212) { tab = stept + (b-192)*128;  woff = 384; outp = ws + WS_TSTEP + (b-192)*128; }
        else              { tab = eqt   + (b-212)*128;  woff = 512; outp = ws + WS_TEQ   + (b-212)*128; acc = bias[j]; }
        #pragma unroll 4
        for (int k = 0; k < 128; ++k)
            acc += tab[k] * W[(woff + k)*128 + j];
        outp[j] = f2bf(acc);
    } else {
        const int n = b - 214;   // 0..127
        ws[WS_W2T + n*128 + j] = f2bf(W[(256 + j)*128 + n]);
        if (j < 32)
            ws[WS_WRBFT + n*32 + j] = (j < 6) ? f2bf(Wrbf[j*128 + n]) : (unsigned short)0;
    }
}

// ---------------- Kernel I: per-edge prestage (meta, rbf->bf16, rbf_env) ------
__global__ __launch_bounds__(256)
void index_kernel(const int* __restrict__ Z, const int* __restrict__ stepv,
                  const int* __restrict__ src, const int* __restrict__ dst,
                  const int* __restrict__ equiv, const float* __restrict__ rbf,
                  const float* __restrict__ dvec,
                  unsigned char* __restrict__ wsb, float* __restrict__ out) {
    __shared__ float rl[1536];
    __shared__ float el[1536];
    const int t = threadIdx.x;
    const int B0 = blockIdx.x * 256;
    const int e = B0 + t;
    // coalesced rbf stage
    #pragma unroll
    for (int i = 0; i < 6; ++i) rl[t + i*256] = rbf[B0*6 + t + i*256];
    const int s  = src[e];
    const int dd = dst[e];
    const int qe = equiv[e];
    const float x = dvec[e] * 0.2f;
    int4* meta = (int4*)(wsb + WSB_META);
    meta[e] = make_int4(Z[s]*128, Z[dd]*128, stepv[s]*128, qe*128);
    // envelope * bessel into LDS (coalesced write-out later)
    const float inv = __builtin_amdgcn_rcpf(x);
    const float x2 = x*x;
    const float x5 = x2*x2*x;
    const float env = inv + x5*(-28.f + x*(48.f - 21.f*x));
    #pragma unroll
    for (int rr = 0; rr < 6; ++rr)
        el[t*6 + rr] = env * __sinf(x * (3.14159265358979f * (rr + 1))) * inv;
    __syncthreads();
    // rbf -> bf16 x8 (K-padded)
    ushx8 v;
    #pragma unroll
    for (int k = 0; k < 6; ++k) v[k] = f2bf(rl[t*6 + k]);
    v[6] = 0; v[7] = 0;
    ((ushx8*)(wsb + WSB_RBF8))[e] = v;
    #pragma unroll
    for (int i = 0; i < 6; ++i)
        __builtin_nontemporal_store(el[t + i*256],
            &out[(long)E_EDGES*128 + B0*6 + t + i*256]);
}

// ---------------- Kernel M: persistent fused edge kernel ----------------------
// T14 split: next tile's meta/rbf8 prefetched to regs at loop top, published to
// LDS after the mid-barrier; phase 1a/1b consume from LDS (broadcast, low lat).
__global__ __launch_bounds__(256, 3)
void edge_kernel(const unsigned short* __restrict__ ws,
                 const unsigned char* __restrict__ wsb,
                 const float* __restrict__ brbf_g, float* __restrict__ out) {
    __shared__ alignas(16) unsigned short rbf_a[TILE*136];  // 17.0 KB
    __shared__ alignas(16) float sumbuf[TILE*132];          // 33.0 KB
    __shared__ alignas(16) int4  meta_l[TILE];              // 1 KB
    __shared__ alignas(16) int   rbf8_l[256];               // 1 KB (ushx8[64])
    // total 52 KB -> 3 blocks/CU

    const int t = threadIdx.x;
    const int lane = t & 63;
    const int w = t >> 6;
    const int q = lane >> 4;
    const int r = lane & 15;
    const int mh = w >> 1;        // edge sub-tile [mh*16, +16)
    const int nh = w & 1;         // col half [nh*64, +64)
    const int arow = mh*16 + r;

    const unsigned short* W2T = ws + WS_W2T;
    const unsigned short* WRB = ws + WS_WRBFT;
    const int* g_meta_i = (const int*)(wsb + WSB_META);
    const int* g_rbf8_i = (const int*)(wsb + WSB_RBF8);

    // block-invariant B-fragments in VGPRs
    short8 w2f[16];
    short8 wrbf[4];
    float  brbf[4];
    #pragma unroll
    for (int nt = 0; nt < 4; ++nt) {
        const int n = nh*64 + nt*16 + r;
        #pragma unroll
        for (int ks = 0; ks < 4; ++ks)
            w2f[nt*4+ks] = *(const short8*)(W2T + n*128 + ks*32 + q*8);
        wrbf[nt] = *(const short8*)(WRB + n*32 + q*8);
        brbf[nt] = brbf_g[n];
    }

    // phase-1a coalesced-gather coordinates: 16 lanes cover one 256 B table row
    const int el8 = t >> 4;          // edge sub-index 0..15
    const int c0  = (t & 15) * 8;    // col chunk (8 ushorts = 16 B)

    // ---- prologue: stage first tile's meta/rbf8 into LDS ----
    {
        const int b4 = blockIdx.x * (TILE * 4);   // 4 dwords per edge
        ((int*)meta_l)[t] = g_meta_i[b4 + t];
        rbf8_l[t]         = g_rbf8_i[b4 + t];
        __syncthreads();
    }

    for (int tile = blockIdx.x; tile < NTILES; tile += gridDim.x) {
        const int base = tile * TILE;
        const int tnext = tile + gridDim.x;
        const int tclamp = (tnext < NTILES) ? tnext : tile;
        const int nb4 = tclamp * (TILE * 4);

        // ---- issue next-tile prefetch (independent; lands by mid-barrier) ----
        const int mnext = g_meta_i[nb4 + t];
        const int rnext = g_rbf8_i[nb4 + t];

        // ---- phase 1a: table-sum prestage, coalesced row reads ----
        #pragma unroll
        for (int i = 0; i < 4; ++i) {
            const int e = i*16 + el8;
            const int4 mo = meta_l[e];                 // LDS broadcast
            ushx8 u0 = *(const ushx8*)(ws + WS_TSRC  + mo.x + c0);
            ushx8 u1 = *(const ushx8*)(ws + WS_TDST  + mo.y + c0);
            ushx8 u2 = *(const ushx8*)(ws + WS_TSTEP + mo.z + c0);
            ushx8 u3 = *(const ushx8*)(ws + WS_TEQ   + mo.w + c0);
            float* srow = sumbuf + e*132 + c0;
            f32x4 sv0, sv1;
            #pragma unroll
            for (int k = 0; k < 4; ++k) {
                sv0[k] = bf2f(u0[k])   + bf2f(u1[k])   + bf2f(u2[k])   + bf2f(u3[k]);
                sv1[k] = bf2f(u0[k+4]) + bf2f(u1[k+4]) + bf2f(u2[k+4]) + bf2f(u3[k+4]);
            }
            *(f32x4*)(srow)     = sv0;
            *(f32x4*)(srow + 4) = sv1;
        }

        // ---- phase 1b: mini-MFMA rbf_a = silu(rbf @ W_rbf + b), A from LDS ----
        {
            short8 a0 = (short8)0;
            if (q == 0) a0 = ((const short8*)rbf8_l)[arow];
            #pragma unroll
            for (int nt = 0; nt < 4; ++nt) {
                const float bb = brbf[nt];
                f32x4 c = {bb, bb, bb, bb};
                c = __builtin_amdgcn_mfma_f32_16x16x32_bf16(a0, wrbf[nt], c, 0, 0, 0);
                const int col = nh*64 + nt*16 + r;
                #pragma unroll
                for (int reg = 0; reg < 4; ++reg)
                    rbf_a[(mh*16 + q*4 + reg)*136 + col] = f2bf(silu_f(c[reg]));
            }
        }
        __syncthreads();

        // ---- publish next tile's meta/rbf8 (regions not read again this iter)
        ((int*)meta_l)[t] = mnext;
        rbf8_l[t]         = rnext;

        // ---- phase 2: main MFMA (C init = table sums), silu, direct stores ----
        f32x4 acc[4];
        #pragma unroll
        for (int nt = 0; nt < 4; ++nt) {
            const int col = nh*64 + nt*16 + r;
            #pragma unroll
            for (int reg = 0; reg < 4; ++reg)
                acc[nt][reg] = sumbuf[(mh*16 + q*4 + reg)*132 + col];
        }
        #pragma unroll
        for (int ks = 0; ks < 4; ++ks) {
            short8 a = *(const short8*)(rbf_a + arow*136 + ks*32 + q*8);
            #pragma unroll
            for (int nt = 0; nt < 4; ++nt)
                acc[nt] = __builtin_amdgcn_mfma_f32_16x16x32_bf16(a, w2f[nt*4+ks], acc[nt], 0, 0, 0);
        }
        #pragma unroll
        for (int nt = 0; nt < 4; ++nt) {
            const int col = nh*64 + nt*16 + r;
            #pragma unroll
            for (int reg = 0; reg < 4; ++reg)
                __builtin_nontemporal_store(silu_f(acc[nt][reg]),
                    &out[(long)(base + mh*16 + q*4 + reg)*128 + col]);
        }
        __syncthreads();   // protect sumbuf/rbf_a + publish meta_l/rbf8_l
    }
}

extern "C" void kernel_launch(void* const* d_in, const int* in_sizes, int n_in,
                              void* d_out, int out_size, void* d_ws, size_t ws_size,
                              hipStream_t stream) {
    const int*   Z     = (const int*)d_in[0];
    const int*   stepv = (const int*)d_in[1];
    const int*   src   = (const int*)d_in[2];
    const int*   dst   = (const int*)d_in[3];
    const int*   equiv = (const int*)d_in[4];
    const float* rbf   = (const float*)d_in[5];
    const float* dvec  = (const float*)d_in[6];
    const float* emb   = (const float*)d_in[7];
    const float* stept = (const float*)d_in[8];
    const float* eqt   = (const float*)d_in[9];
    const float* Wrbf  = (const float*)d_in[10];
    const float* brbf  = (const float*)d_in[11];
    const float* W     = (const float*)d_in[12];
    const float* bias  = (const float*)d_in[13];
    unsigned short* ws = (unsigned short*)d_ws;
    unsigned char* wsb = (unsigned char*)d_ws;
    float* out = (float*)d_out;

    precompute_kernel<<<342, 128, 0, stream>>>(emb, stept, eqt, Wrbf, W, bias, ws);
    index_kernel<<<3125, 256, 0, stream>>>(Z, stepv, src, dst, equiv, rbf, dvec, wsb, out);
    edge_kernel<<<768, 256, 0, stream>>>(ws, wsb, brbf, out);
}

// Round 5
// 494.473 us; speedup vs baseline: 1.0630x; 1.0070x over previous
//
#include <hip/hip_runtime.h>

typedef __attribute__((ext_vector_type(8))) short short8;
typedef __attribute__((ext_vector_type(4))) float f32x4;
typedef __attribute__((ext_vector_type(4))) unsigned short ushx4;
typedef __attribute__((ext_vector_type(8))) unsigned short ushx8;

#define E_EDGES 800000
#define TILE 64
#define NTILES (E_EDGES / TILE)   // 12500 exact

// ws layout, ushort units (tables)
#define WS_TSRC 0
#define WS_TDST 12288
#define WS_TSTEP 24576
#define WS_TEQ 27136
#define WS_W2T 27392      // [n=0..127][k=0..127], W2T[n][k] = W[256+k][n]
#define WS_WRBFT 43776    // [n=0..127][k=0..31],  zero-padded past k=6
// byte offsets for per-edge prestage (tables end at 95744 B)
#define WSB_META 131072u                    // int4[E] = 12.8 MB
#define WSB_RBF8 (WSB_META + 16u*E_EDGES)   // ushx8[E] = 12.8 MB

#define IDX_BLOCKS 3125                     // index part of merged prestage grid
#define PRE_BLOCKS 171                      // 171*2 = 342 precompute slices

__device__ __forceinline__ unsigned short f2bf(float f) {
    unsigned int u = __float_as_uint(f);
    u += 0x7fffu + ((u >> 16) & 1u);   // RNE
    return (unsigned short)(u >> 16);
}
__device__ __forceinline__ float bf2f(unsigned short u) {
    return __uint_as_float(((unsigned int)u) << 16);
}
__device__ __forceinline__ float silu_f(float v) {
    return v * __builtin_amdgcn_rcpf(1.0f + __expf(-v));
}
// LDS-only barrier: keeps global stores/loads in flight across the barrier.
// Single asm block w/ memory clobber: no memory op can be scheduled across it.
__device__ __forceinline__ void barrier_lds() {
    asm volatile("s_waitcnt lgkmcnt(0)\n\ts_barrier" ::: "memory");
}

// ------------- Merged prestage kernel: index part + precompute part ----------
__global__ __launch_bounds__(256)
void prestage_kernel(const int* __restrict__ Z, const int* __restrict__ stepv,
                     const int* __restrict__ src, const int* __restrict__ dst,
                     const int* __restrict__ equiv, const float* __restrict__ rbf,
                     const float* __restrict__ dvec,
                     const float* __restrict__ emb, const float* __restrict__ stept,
                     const float* __restrict__ eqt, const float* __restrict__ Wrbf,
                     const float* __restrict__ W, const float* __restrict__ bias,
                     unsigned short* __restrict__ ws, unsigned char* __restrict__ wsb,
                     float* __restrict__ out) {
    const int t = threadIdx.x;
    if (blockIdx.x < IDX_BLOCKS) {
        // ---------------- index part: meta, rbf->bf16, rbf_env ----------------
        __shared__ float rl[1536];
        __shared__ float el[1536];
        const int B0 = blockIdx.x * 256;
        const int e = B0 + t;
        #pragma unroll
        for (int i = 0; i < 6; ++i) rl[t + i*256] = rbf[B0*6 + t + i*256];
        const int s  = src[e];
        const int dd = dst[e];
        const int qe = equiv[e];
        const float x = dvec[e] * 0.2f;
        int4* meta = (int4*)(wsb + WSB_META);
        meta[e] = make_int4(Z[s]*128, Z[dd]*128, stepv[s]*128, qe*128);
        const float inv = __builtin_amdgcn_rcpf(x);
        const float x2 = x*x;
        const float x5 = x2*x2*x;
        const float env = inv + x5*(-28.f + x*(48.f - 21.f*x));
        #pragma unroll
        for (int rr = 0; rr < 6; ++rr)
            el[t*6 + rr] = env * __sinf(x * (3.14159265358979f * (rr + 1))) * inv;
        __syncthreads();
        ushx8 v;
        #pragma unroll
        for (int k = 0; k < 6; ++k) v[k] = f2bf(rl[t*6 + k]);
        v[6] = 0; v[7] = 0;
        ((ushx8*)(wsb + WSB_RBF8))[e] = v;
        #pragma unroll
        for (int i = 0; i < 6; ++i)
            __builtin_nontemporal_store(el[t + i*256],
                &out[(long)E_EDGES*128 + B0*6 + t + i*256]);
    } else {
        // ------------- precompute part: fold gathers through W ---------------
        const int bb = (blockIdx.x - IDX_BLOCKS) * 2 + (t >> 7);   // 0..341
        const int j = t & 127;
        if (bb < 214) {
            const float* tab; int woff; unsigned short* outp; float acc = 0.f;
            if (bb < 96)       { tab = emb   + bb*128;        woff = 0;   outp = ws + WS_TSRC  + bb*128; }
            else if (bb < 192) { tab = emb   + (bb-96)*128;   woff = 128; outp = ws + WS_TDST  + (bb-96)*128; }
            else if (bb < 212) { tab = stept + (bb-192)*128;  woff = 384; outp = ws + WS_TSTEP + (bb-192)*128; }
            else               { tab = eqt   + (bb-212)*128;  woff = 512; outp = ws + WS_TEQ   + (bb-212)*128; acc = bias[j]; }
            #pragma unroll 4
            for (int k = 0; k < 128; ++k)
                acc += tab[k] * W[(woff + k)*128 + j];
            outp[j] = f2bf(acc);
        } else {
            const int n = bb - 214;   // 0..127
            ws[WS_W2T + n*128 + j] = f2bf(W[(256 + j)*128 + n]);
            if (j < 32)
                ws[WS_WRBFT + n*32 + j] = (j < 6) ? f2bf(Wrbf[j*128 + n]) : (unsigned short)0;
        }
    }
}

// ---------------- Kernel M: persistent fused edge kernel ----------------------
// T14 split: next tile's meta/rbf8 prefetched to regs at loop top, published to
// LDS after the mid-barrier; phase 1a/1b consume from LDS. Barriers are
// LDS-only (lgkmcnt) so the 16 out-stores stay in flight across iterations.
__global__ __launch_bounds__(256, 3)
void edge_kernel(const unsigned short* __restrict__ ws,
                 const unsigned char* __restrict__ wsb,
                 const float* __restrict__ brbf_g, float* __restrict__ out) {
    __shared__ alignas(16) unsigned short rbf_a[TILE*136];  // 17.0 KB
    __shared__ alignas(16) float sumbuf[TILE*132];          // 33.0 KB
    __shared__ alignas(16) int4  meta_l[TILE];              // 1 KB
    __shared__ alignas(16) int   rbf8_l[256];               // 1 KB (ushx8[64])
    // total 52 KB -> 3 blocks/CU

    const int t = threadIdx.x;
    const int lane = t & 63;
    const int w = t >> 6;
    const int q = lane >> 4;
    const int r = lane & 15;
    const int mh = w >> 1;        // edge sub-tile [mh*16, +16)
    const int nh = w & 1;         // col half [nh*64, +64)
    const int arow = mh*16 + r;

    const unsigned short* W2T = ws + WS_W2T;
    const unsigned short* WRB = ws + WS_WRBFT;
    const int* g_meta_i = (const int*)(wsb + WSB_META);
    const int* g_rbf8_i = (const int*)(wsb + WSB_RBF8);

    // block-invariant B-fragments in VGPRs
    short8 w2f[16];
    short8 wrbf[4];
    float  brbf[4];
    #pragma unroll
    for (int nt = 0; nt < 4; ++nt) {
        const int n = nh*64 + nt*16 + r;
        #pragma unroll
        for (int ks = 0; ks < 4; ++ks)
            w2f[nt*4+ks] = *(const short8*)(W2T + n*128 + ks*32 + q*8);
        wrbf[nt] = *(const short8*)(WRB + n*32 + q*8);
        brbf[nt] = brbf_g[n];
    }

    // phase-1a coalesced-gather coordinates: 16 lanes cover one 256 B table row
    const int el8 = t >> 4;          // edge sub-index 0..15
    const int c0  = (t & 15) * 8;    // col chunk (8 ushorts = 16 B)

    // ---- prologue: stage first tile's meta/rbf8 into LDS ----
    {
        const int b4 = blockIdx.x * (TILE * 4);   // 4 dwords per edge
        ((int*)meta_l)[t] = g_meta_i[b4 + t];
        rbf8_l[t]         = g_rbf8_i[b4 + t];
        barrier_lds();
    }

    for (int tile = blockIdx.x; tile < NTILES; tile += gridDim.x) {
        const int base = tile * TILE;
        const int tnext = tile + gridDim.x;
        const int tclamp = (tnext < NTILES) ? tnext : tile;
        const int nb4 = tclamp * (TILE * 4);

        // ---- issue next-tile prefetch (independent; lands by mid-barrier) ----
        const int mnext = g_meta_i[nb4 + t];
        const int rnext = g_rbf8_i[nb4 + t];

        // ---- phase 1a: table-sum prestage, coalesced row reads ----
        #pragma unroll
        for (int i = 0; i < 4; ++i) {
            const int e = i*16 + el8;
            const int4 mo = meta_l[e];                 // LDS broadcast
            ushx8 u0 = *(const ushx8*)(ws + WS_TSRC  + mo.x + c0);
            ushx8 u1 = *(const ushx8*)(ws + WS_TDST  + mo.y + c0);
            ushx8 u2 = *(const ushx8*)(ws + WS_TSTEP + mo.z + c0);
            ushx8 u3 = *(const ushx8*)(ws + WS_TEQ   + mo.w + c0);
            float* srow = sumbuf + e*132 + c0;
            f32x4 sv0, sv1;
            #pragma unroll
            for (int k = 0; k < 4; ++k) {
                sv0[k] = bf2f(u0[k])   + bf2f(u1[k])   + bf2f(u2[k])   + bf2f(u3[k]);
                sv1[k] = bf2f(u0[k+4]) + bf2f(u1[k+4]) + bf2f(u2[k+4]) + bf2f(u3[k+4]);
            }
            *(f32x4*)(srow)     = sv0;
            *(f32x4*)(srow + 4) = sv1;
        }

        // ---- phase 1b: mini-MFMA rbf_a = silu(rbf @ W_rbf + b), A from LDS ----
        {
            short8 a0 = (short8)0;
            if (q == 0) a0 = ((const short8*)rbf8_l)[arow];
            #pragma unroll
            for (int nt = 0; nt < 4; ++nt) {
                const float bb = brbf[nt];
                f32x4 c = {bb, bb, bb, bb};
                c = __builtin_amdgcn_mfma_f32_16x16x32_bf16(a0, wrbf[nt], c, 0, 0, 0);
                const int col = nh*64 + nt*16 + r;
                #pragma unroll
                for (int reg = 0; reg < 4; ++reg)
                    rbf_a[(mh*16 + q*4 + reg)*136 + col] = f2bf(silu_f(c[reg]));
            }
        }
        barrier_lds();

        // ---- publish next tile's meta/rbf8 (regions not read again this iter)
        ((int*)meta_l)[t] = mnext;
        rbf8_l[t]         = rnext;

        // ---- phase 2: main MFMA (C init = table sums), silu, direct stores ----
        f32x4 acc[4];
        #pragma unroll
        for (int nt = 0; nt < 4; ++nt) {
            const int col = nh*64 + nt*16 + r;
            #pragma unroll
            for (int reg = 0; reg < 4; ++reg)
                acc[nt][reg] = sumbuf[(mh*16 + q*4 + reg)*132 + col];
        }
        #pragma unroll
        for (int ks = 0; ks < 4; ++ks) {
            short8 a = *(const short8*)(rbf_a + arow*136 + ks*32 + q*8);
            #pragma unroll
            for (int nt = 0; nt < 4; ++nt)
                acc[nt] = __builtin_amdgcn_mfma_f32_16x16x32_bf16(a, w2f[nt*4+ks], acc[nt], 0, 0, 0);
        }
        #pragma unroll
        for (int nt = 0; nt < 4; ++nt) {
            const int col = nh*64 + nt*16 + r;
            #pragma unroll
            for (int reg = 0; reg < 4; ++reg)
                __builtin_nontemporal_store(silu_f(acc[nt][reg]),
                    &out[(long)(base + mh*16 + q*4 + reg)*128 + col]);
        }
        barrier_lds();   // protect sumbuf/rbf_a + publish meta_l/rbf8_l
    }
}

extern "C" void kernel_launch(void* const* d_in, const int* in_sizes, int n_in,
                              void* d_out, int out_size, void* d_ws, size_t ws_size,
                              hipStream_t stream) {
    const int*   Z     = (const int*)d_in[0];
    const int*   stepv = (const int*)d_in[1];
    const int*   src   = (const int*)d_in[2];
    const int*   dst   = (const int*)d_in[3];
    const int*   equiv = (const int*)d_in[4];
    const float* rbf   = (const float*)d_in[5];
    const float* dvec  = (const float*)d_in[6];
    const float* emb   = (const float*)d_in[7];
    const float* stept = (const float*)d_in[8];
    const float* eqt   = (const float*)d_in[9];
    const float* Wrbf  = (const float*)d_in[10];
    const float* brbf  = (const float*)d_in[11];
    const float* W     = (const float*)d_in[12];
    const float* bias  = (const float*)d_in[13];
    unsigned short* ws = (unsigned short*)d_ws;
    unsigned char* wsb = (unsigned char*)d_ws;
    float* out = (float*)d_out;

    prestage_kernel<<<IDX_BLOCKS + PRE_BLOCKS, 256, 0, stream>>>(
        Z, stepv, src, dst, equiv, rbf, dvec,
        emb, stept, eqt, Wrbf, W, bias, ws, wsb, out);
    edge_kernel<<<768, 256, 0, stream>>>(ws, wsb, brbf, out);
}